// Round 1
// baseline (3381.041 us; speedup 1.0000x reference)
//
#include <hip/hip_runtime.h>
#include <hip/hip_bf16.h>
#include <math.h>

// SplineConv GNN: out = descs + 0.1 * conv2(relu(conv1(descs)))
// conv(x):  Z[n,k,:] = x[n] @ W[k] (25 bins) and x @ root as bin 25 -> one GEMM
//           msg[e] = sum_s basis_s * Z[tails[e], wi_s];  agg = segment_max(msg, heads)
//           y = fix(agg) + Z[:,25,:] + bias
// All GEMM compute in bf16 MFMA (fp32 accum); threshold 0.104 absmax is bf16-tolerant.

#define DN 4096
#define DE 65536
#define DF 1024
#define NMAT 26
#define NCOLS (NMAT * DF)   // 26624

typedef __attribute__((ext_vector_type(8))) short short8;
typedef __attribute__((ext_vector_type(4))) float f32x4;

__device__ __forceinline__ float bf2f(unsigned short u) {
    return __uint_as_float(((unsigned int)u) << 16);
}
__device__ __forceinline__ unsigned short f2bf(float f) {
    unsigned int x = __float_as_uint(f);
    x += 0x7fffu + ((x >> 16) & 1u);   // RTNE (no NaN inputs in this pipeline)
    return (unsigned short)(x >> 16);
}
__device__ __forceinline__ void gld16(const unsigned short* g, unsigned short* l) {
    __builtin_amdgcn_global_load_lds(
        (const __attribute__((address_space(1))) unsigned int*)g,
        (__attribute__((address_space(3))) unsigned int*)l, 16, 0, 0);
}
// float atomic max via sign-split; agg initialized to -inf
__device__ __forceinline__ void atomicMaxF(float* addr, float val) {
    if (val >= 0.f) atomicMax((int*)addr, __float_as_int(val));
    else            atomicMin((unsigned int*)addr, __float_as_uint(val));
}

// ---------------- fp32 -> bf16 convert (x / h1 input) ----------------
__global__ void k_convert_x(const float* __restrict__ x, unsigned short* __restrict__ xb) {
    int i = (blockIdx.x * blockDim.x + threadIdx.x) * 4;   // grid sized exactly
    float4 v = *(const float4*)(x + i);
    union { unsigned short u[4]; unsigned long long ll; } o;
    o.u[0] = f2bf(v.x); o.u[1] = f2bf(v.y); o.u[2] = f2bf(v.z); o.u[3] = f2bf(v.w);
    *(unsigned long long*)(xb + i) = o.ll;
}

__global__ void k_init_agg(float* __restrict__ agg) {
    int i = (blockIdx.x * blockDim.x + threadIdx.x) * 4;
    float ninf = -__builtin_huge_valf();
    float4 v = make_float4(ninf, ninf, ninf, ninf);
    *(float4*)(agg + i) = v;
}

// ---------------- W[k][i][o] fp32  ->  Wbt[k][o][i] bf16 (B^T, K-contiguous) ----------------
__global__ void k_transpose_w(const float* __restrict__ W, const float* __restrict__ root,
                              unsigned short* __restrict__ Wbt) {
    __shared__ float tile[64][65];
    int mat = blockIdx.z;
    const float* src = (mat < 25) ? (W + (size_t)mat * DF * DF) : root;
    unsigned short* dst = Wbt + (size_t)mat * DF * DF;
    int i0 = blockIdx.x * 64;          // i (GEMM-K) block
    int o0 = blockIdx.y * 64;          // o (GEMM-N) block
    int tx = threadIdx.x & 63, ty = threadIdx.x >> 6;
#pragma unroll
    for (int j = 0; j < 16; ++j) {
        int r = j * 4 + ty;
        tile[r][tx] = src[(size_t)(i0 + r) * DF + o0 + tx];
    }
    __syncthreads();
#pragma unroll
    for (int j = 0; j < 16; ++j) {
        int c = j * 4 + ty;
        dst[(size_t)(o0 + c) * DF + i0 + tx] = f2bf(tile[tx][c]);   // stride-65 LDS read: conflict-free
    }
}

// ---------------- GEMM: C[M=4096, N=26624] = A[M,1024] @ B, B given as B^T rows (Wbt) ----------------
// m97 structure: 128x128 tile, BK=32, 4 waves (2x2 of 64x64), global_load_lds width 16.
__global__ __launch_bounds__(256)
void k_gemm(const unsigned short* __restrict__ A,   // [4096][1024] bf16
            const unsigned short* __restrict__ B,   // [26624][1024] bf16 (= W^T blocks)
            unsigned short* __restrict__ C)         // [4096][26624] bf16
{
    __shared__ unsigned short As[128 * 32];
    __shared__ unsigned short Bs[128 * 32];
    const int tid = threadIdx.x;
    const int w = tid >> 6, ln = tid & 63;
    const int wr = w >> 1, wc = w & 1;
    const int bm = blockIdx.x, bn = blockIdx.y;

    f32x4 acc[4][4];
#pragma unroll
    for (int m = 0; m < 4; ++m)
#pragma unroll
        for (int n = 0; n < 4; ++n) acc[m][n] = (f32x4){0.f, 0.f, 0.f, 0.f};

    const size_t abase = (size_t)bm * 128 * 1024;
    const size_t bbase = (size_t)bn * 128 * 1024;
    const int k0 = (ln >> 4) * 8;
    const int rsel = ln & 15;

    for (int kk = 0; kk < 32; ++kk) {
        const int kbase = kk * 32;
#pragma unroll
        for (int j = 0; j < 2; ++j) {
            int chunk = j * 4 + w;                  // wave-uniform LDS chunk
            int byteoff = chunk * 1024 + ln * 16;   // lane's byte in tile
            int row = byteoff >> 6;                 // 64 B per row (32 bf16)
            int ke = (byteoff & 63) >> 1;
            gld16(A + abase + (size_t)row * 1024 + kbase + ke, &As[chunk * 512]);
            gld16(B + bbase + (size_t)row * 1024 + kbase + ke, &Bs[chunk * 512]);
        }
        __syncthreads();   // vmcnt(0) drain + barrier
        short8 af[4], bf[4];
#pragma unroll
        for (int m = 0; m < 4; ++m)
            af[m] = *(const short8*)&As[(wr * 64 + m * 16 + rsel) * 32 + k0];
#pragma unroll
        for (int n = 0; n < 4; ++n)
            bf[n] = *(const short8*)&Bs[(wc * 64 + n * 16 + rsel) * 32 + k0];
#pragma unroll
        for (int m = 0; m < 4; ++m)
#pragma unroll
            for (int n = 0; n < 4; ++n)
                acc[m][n] = __builtin_amdgcn_mfma_f32_16x16x32_bf16(af[m], bf[n], acc[m][n], 0, 0, 0);
        __syncthreads();
    }

    // epilogue: C/D layout col=lane&15, row=(lane>>4)*4+reg  [measured m89/m91]
    const int r0 = (ln >> 4) * 4;
#pragma unroll
    for (int m = 0; m < 4; ++m) {
#pragma unroll
        for (int n = 0; n < 4; ++n) {
            int row = bm * 128 + wr * 64 + m * 16 + r0;
            int col = bn * 128 + wc * 64 + n * 16 + (ln & 15);
#pragma unroll
            for (int r = 0; r < 4; ++r)
                C[(size_t)(row + r) * NCOLS + col] = f2bf(acc[m][n][r]);
        }
    }
}

// ---------------- per-edge: basis-weighted gather of Z rows + atomic scatter-max ----------------
__global__ void k_edge(const float* __restrict__ pts,
                       const int* __restrict__ tails, const int* __restrict__ heads,
                       const unsigned short* __restrict__ Z, float* __restrict__ agg)
{
    const int e = blockIdx.x;
    const int t = tails[e], h = heads[e];
    const float ptx = pts[2 * t], pty = pts[2 * t + 1];
    const float phx = pts[2 * h], phy = pts[2 * h + 1];
    float p0 = fminf(fmaxf((ptx - phx) * (0.5f / 256.f) + 0.5f, 0.f), 1.f);
    float p1 = fminf(fmaxf((pty - phy) * (0.5f / 256.f) + 0.5f, 0.f), 1.f);
    float v0 = p0 * 4.f, v1 = p1 * 4.f;
    float f0 = fminf(floorf(v0), 3.f), f1 = fminf(floorf(v1), 3.f);
    float fr0 = v0 - f0, fr1 = v1 - f1;
    int i0 = (int)f0, i1 = (int)f1;

    const int c = threadIdx.x * 4;
    float m0 = 0.f, m1 = 0.f, m2 = 0.f, m3 = 0.f;
    const unsigned short* zt = Z + (size_t)t * NCOLS + c;
#pragma unroll
    for (int s = 0; s < 4; ++s) {
        int b0 = s & 1, b1 = (s >> 1) & 1;
        float basis = (b0 ? fr0 : 1.f - fr0) * (b1 ? fr1 : 1.f - fr1);
        int wi = (i0 + b0) + (i1 + b1) * 5;
        unsigned long long q = *(const unsigned long long*)(zt + wi * DF);   // 4 bf16, 8B
        m0 += basis * bf2f((unsigned short)q);
        m1 += basis * bf2f((unsigned short)(q >> 16));
        m2 += basis * bf2f((unsigned short)(q >> 32));
        m3 += basis * bf2f((unsigned short)(q >> 48));
    }
    float* ap = agg + (size_t)h * DF + c;
    atomicMaxF(ap + 0, m0);
    atomicMaxF(ap + 1, m1);
    atomicMaxF(ap + 2, m2);
    atomicMaxF(ap + 3, m3);
}

// ---------------- layer-1 epilogue: h1 = relu(fix(agg) + Zroot + bias); also re-init agg ----------------
__global__ void k_combine1(float* __restrict__ agg, const unsigned short* __restrict__ Z,
                           const float* __restrict__ bias, unsigned short* __restrict__ h1b)
{
    int i = blockIdx.x * blockDim.x + threadIdx.x;
    int n = i >> 10, cpos = i & 1023;
    float a = agg[i];
    if (a < -3.0e38f) a = 0.f;                       // empty segment (-inf) -> 0
    float zr = bf2f(Z[(size_t)n * NCOLS + 25 * DF + cpos]);
    float hv = fmaxf(a + zr + bias[cpos], 0.f);
    h1b[i] = f2bf(hv);
    agg[i] = -__builtin_huge_valf();                 // reset for layer 2
}

// ---------------- layer-2 epilogue: out = descs + 0.1*(fix(agg) + Zroot + bias) ----------------
__global__ void k_combine2(const float* __restrict__ descs, const float* __restrict__ agg,
                           const unsigned short* __restrict__ Z, const float* __restrict__ bias,
                           float* __restrict__ out)
{
    int i = blockIdx.x * blockDim.x + threadIdx.x;
    int n = i >> 10, cpos = i & 1023;
    float a = agg[i];
    if (a < -3.0e38f) a = 0.f;
    float zr = bf2f(Z[(size_t)n * NCOLS + 25 * DF + cpos]);
    out[i] = descs[i] + 0.1f * (a + zr + bias[cpos]);
}

extern "C" void kernel_launch(void* const* d_in, const int* in_sizes, int n_in,
                              void* d_out, int out_size, void* d_ws, size_t ws_size,
                              hipStream_t stream) {
    const float* descs = (const float*)d_in[0];
    const float* pts   = (const float*)d_in[1];
    const float* W1    = (const float*)d_in[2];
    const float* root1 = (const float*)d_in[3];
    const float* bias1 = (const float*)d_in[4];
    const float* W2    = (const float*)d_in[5];
    const float* root2 = (const float*)d_in[6];
    const float* bias2 = (const float*)d_in[7];
    const int* tails   = (const int*)d_in[8];
    const int* heads   = (const int*)d_in[9];
    float* out = (float*)d_out;

    char* ws = (char*)d_ws;
    unsigned short* Wbt = (unsigned short*)ws;  ws += (size_t)NMAT * DF * DF * 2;   // 54.5 MB
    unsigned short* xb  = (unsigned short*)ws;  ws += (size_t)DN * DF * 2;          //  8.4 MB
    unsigned short* h1b = (unsigned short*)ws;  ws += (size_t)DN * DF * 2;          //  8.4 MB
    float*          agg = (float*)ws;           ws += (size_t)DN * DF * 4;          // 16.8 MB
    unsigned short* Z   = (unsigned short*)ws;  ws += (size_t)DN * NCOLS * 2;       // 218 MB

    // ---- layer 1 ----
    k_convert_x<<<DN * DF / 4 / 256, 256, 0, stream>>>(descs, xb);
    k_init_agg<<<DN * DF / 4 / 256, 256, 0, stream>>>(agg);
    k_transpose_w<<<dim3(16, 16, NMAT), 256, 0, stream>>>(W1, root1, Wbt);
    k_gemm<<<dim3(DN / 128, NCOLS / 128), 256, 0, stream>>>(xb, Wbt, Z);
    k_edge<<<DE, 256, 0, stream>>>(pts, tails, heads, Z, agg);
    k_combine1<<<DN * DF / 256, 256, 0, stream>>>(agg, Z, bias1, h1b);
    // ---- layer 2 ----
    k_transpose_w<<<dim3(16, 16, NMAT), 256, 0, stream>>>(W2, root2, Wbt);
    k_gemm<<<dim3(DN / 128, NCOLS / 128), 256, 0, stream>>>(h1b, Wbt, Z);
    k_edge<<<DE, 256, 0, stream>>>(pts, tails, heads, Z, agg);
    k_combine2<<<DN * DF / 256, 256, 0, stream>>>(descs, agg, Z, bias2, out);
}

// Round 3
// 942.466 us; speedup vs baseline: 3.5874x; 3.5874x over previous
//
#include <hip/hip_runtime.h>
#include <hip/hip_bf16.h>
#include <math.h>

// SplineConv GNN: out = descs + 0.1 * conv2(relu(conv1(descs)))
// Round 1 -> 2 change: per-edge global atomic scatter-max (67M atomics, 2x1293us)
// replaced by device-built CSR over heads + register-resident segment max
// (one block per destination node). Epilogues fused into the agg kernels.
// (Round 2 resubmission — previous bench hit GPUAcquisitionTimeout, never ran.)

#define DN 4096
#define DE 65536
#define DF 1024
#define NMAT 26
#define NCOLS (NMAT * DF)   // 26624

typedef __attribute__((ext_vector_type(8))) short short8;
typedef __attribute__((ext_vector_type(4))) float f32x4;
typedef unsigned long long ull;

__device__ __forceinline__ float bf2f(unsigned short u) {
    return __uint_as_float(((unsigned int)u) << 16);
}
__device__ __forceinline__ unsigned short f2bf(float f) {
    unsigned int x = __float_as_uint(f);
    x += 0x7fffu + ((x >> 16) & 1u);   // RTNE (no NaN inputs in this pipeline)
    return (unsigned short)(x >> 16);
}
__device__ __forceinline__ void gld16(const unsigned short* g, unsigned short* l) {
    __builtin_amdgcn_global_load_lds(
        (const __attribute__((address_space(1))) unsigned int*)g,
        (__attribute__((address_space(3))) unsigned int*)l, 16, 0, 0);
}

// ---------------- fp32 -> bf16 convert (x input) ----------------
__global__ void k_convert_x(const float* __restrict__ x, unsigned short* __restrict__ xb) {
    int i = (blockIdx.x * blockDim.x + threadIdx.x) * 4;   // grid sized exactly
    float4 v = *(const float4*)(x + i);
    union { unsigned short u[4]; ull ll; } o;
    o.u[0] = f2bf(v.x); o.u[1] = f2bf(v.y); o.u[2] = f2bf(v.z); o.u[3] = f2bf(v.w);
    *(ull*)(xb + i) = o.ll;
}

// ---------------- CSR build over heads ----------------
__global__ void k_hist(const int* __restrict__ heads, int* __restrict__ cnt) {
    int e = blockIdx.x * blockDim.x + threadIdx.x;
    atomicAdd(&cnt[heads[e]], 1);
}

// single block, 1024 threads, scans 4096 counts -> row_off[0..4096], cursor copy
__global__ __launch_bounds__(1024)
void k_scan(const int* __restrict__ cnt, int* __restrict__ row_off, int* __restrict__ cursor) {
    __shared__ int part[1024];
    int tid = threadIdx.x;
    int base = tid * 4;
    int v[4], s = 0;
#pragma unroll
    for (int j = 0; j < 4; ++j) { v[j] = s; s += cnt[base + j]; }
    part[tid] = s;
    __syncthreads();
    for (int off = 1; off < 1024; off <<= 1) {
        int t = (tid >= off) ? part[tid - off] : 0;
        __syncthreads();
        part[tid] += t;
        __syncthreads();
    }
    int excl = (tid == 0) ? 0 : part[tid - 1];
#pragma unroll
    for (int j = 0; j < 4; ++j) {
        row_off[base + j] = excl + v[j];
        cursor[base + j]  = excl + v[j];
    }
    if (tid == 1023) row_off[4096] = part[1023];
}

// scatter edges into CSR order; precompute per-edge (tail, packed wi, basis4)
__global__ void k_scatter(const float* __restrict__ pts,
                          const int* __restrict__ tails, const int* __restrict__ heads,
                          int* __restrict__ cursor,
                          int2* __restrict__ ei, float4* __restrict__ eb) {
    int e = blockIdx.x * blockDim.x + threadIdx.x;
    int t = tails[e], h = heads[e];
    float ptx = pts[2 * t], pty = pts[2 * t + 1];
    float phx = pts[2 * h], phy = pts[2 * h + 1];
    float p0 = fminf(fmaxf((ptx - phx) * (0.5f / 256.f) + 0.5f, 0.f), 1.f);
    float p1 = fminf(fmaxf((pty - phy) * (0.5f / 256.f) + 0.5f, 0.f), 1.f);
    float v0 = p0 * 4.f, v1 = p1 * 4.f;
    float f0 = fminf(floorf(v0), 3.f), f1 = fminf(floorf(v1), 3.f);
    float fr0 = v0 - f0, fr1 = v1 - f1;
    int i0 = (int)f0, i1 = (int)f1;
    int wi0 = i0 + i1 * 5;          // (b0,b1)=(0,0)
    int wi1 = wi0 + 1;              // (1,0)
    int wi2 = wi0 + 5;              // (0,1)
    int wi3 = wi0 + 6;              // (1,1)
    float4 b;
    b.x = (1.f - fr0) * (1.f - fr1);
    b.y = fr0 * (1.f - fr1);
    b.z = (1.f - fr0) * fr1;
    b.w = fr0 * fr1;
    int pos = atomicAdd(&cursor[h], 1);
    ei[pos] = make_int2(t, wi0 | (wi1 << 8) | (wi2 << 16) | (wi3 << 24));
    eb[pos] = b;
}

// ---------------- W[k][i][o] fp32  ->  Wbt[k][o][i] bf16 (B^T, K-contiguous) ----------------
__global__ void k_transpose_w(const float* __restrict__ W, const float* __restrict__ root,
                              unsigned short* __restrict__ Wbt) {
    __shared__ float tile[64][65];
    int mat = blockIdx.z;
    const float* src = (mat < 25) ? (W + (size_t)mat * DF * DF) : root;
    unsigned short* dst = Wbt + (size_t)mat * DF * DF;
    int i0 = blockIdx.x * 64;
    int o0 = blockIdx.y * 64;
    int tx = threadIdx.x & 63, ty = threadIdx.x >> 6;
#pragma unroll
    for (int j = 0; j < 16; ++j) {
        int r = j * 4 + ty;
        tile[r][tx] = src[(size_t)(i0 + r) * DF + o0 + tx];
    }
    __syncthreads();
#pragma unroll
    for (int j = 0; j < 16; ++j) {
        int c = j * 4 + ty;
        dst[(size_t)(o0 + c) * DF + i0 + tx] = f2bf(tile[tx][c]);
    }
}

// ---------------- GEMM: C[4096, 26624] = A[4096,1024] @ B^T rows ----------------
__global__ __launch_bounds__(256)
void k_gemm(const unsigned short* __restrict__ A,
            const unsigned short* __restrict__ B,
            unsigned short* __restrict__ C)
{
    __shared__ unsigned short As[128 * 32];
    __shared__ unsigned short Bs[128 * 32];
    const int tid = threadIdx.x;
    const int w = tid >> 6, ln = tid & 63;
    const int wr = w >> 1, wc = w & 1;
    const int bm = blockIdx.x, bn = blockIdx.y;

    f32x4 acc[4][4];
#pragma unroll
    for (int m = 0; m < 4; ++m)
#pragma unroll
        for (int n = 0; n < 4; ++n) acc[m][n] = (f32x4){0.f, 0.f, 0.f, 0.f};

    const size_t abase = (size_t)bm * 128 * 1024;
    const size_t bbase = (size_t)bn * 128 * 1024;
    const int k0 = (ln >> 4) * 8;
    const int rsel = ln & 15;

    for (int kk = 0; kk < 32; ++kk) {
        const int kbase = kk * 32;
#pragma unroll
        for (int j = 0; j < 2; ++j) {
            int chunk = j * 4 + w;
            int byteoff = chunk * 1024 + ln * 16;
            int row = byteoff >> 6;
            int ke = (byteoff & 63) >> 1;
            gld16(A + abase + (size_t)row * 1024 + kbase + ke, &As[chunk * 512]);
            gld16(B + bbase + (size_t)row * 1024 + kbase + ke, &Bs[chunk * 512]);
        }
        __syncthreads();
        short8 af[4], bf[4];
#pragma unroll
        for (int m = 0; m < 4; ++m)
            af[m] = *(const short8*)&As[(wr * 64 + m * 16 + rsel) * 32 + k0];
#pragma unroll
        for (int n = 0; n < 4; ++n)
            bf[n] = *(const short8*)&Bs[(wc * 64 + n * 16 + rsel) * 32 + k0];
#pragma unroll
        for (int m = 0; m < 4; ++m)
#pragma unroll
            for (int n = 0; n < 4; ++n)
                acc[m][n] = __builtin_amdgcn_mfma_f32_16x16x32_bf16(af[m], bf[n], acc[m][n], 0, 0, 0);
        __syncthreads();
    }

    const int r0 = (ln >> 4) * 4;
#pragma unroll
    for (int m = 0; m < 4; ++m) {
#pragma unroll
        for (int n = 0; n < 4; ++n) {
            int row = bm * 128 + wr * 64 + m * 16 + r0;
            int col = bn * 128 + wc * 64 + n * 16 + (ln & 15);
#pragma unroll
            for (int r = 0; r < 4; ++r)
                C[(size_t)(row + r) * NCOLS + col] = f2bf(acc[m][n][r]);
        }
    }
}

// ---------------- segment max, one block per destination node; fused epilogue ----------------
// LAYER: 1 -> h1 = relu(max + Zroot + bias) stored bf16
//        2 -> out = descs + 0.1*(max + Zroot + bias) stored fp32
template <int LAYER>
__global__ __launch_bounds__(256)
void k_agg(const int* __restrict__ row_off,
           const int2* __restrict__ ei, const float4* __restrict__ eb,
           const unsigned short* __restrict__ Z,
           const float* __restrict__ bias,
           const float* __restrict__ descs,
           unsigned short* __restrict__ h1b, float* __restrict__ out)
{
    __shared__ int2  sei[64];
    __shared__ float4 seb[64];
    const int n = blockIdx.x;
    const int tid = threadIdx.x;
    const int d = tid * 4;
    const int s0 = row_off[n], s1 = row_off[n + 1];

    float vm0 = -3.3e38f, vm1 = -3.3e38f, vm2 = -3.3e38f, vm3 = -3.3e38f;

    for (int chunk = s0; chunk < s1; chunk += 64) {
        int cnum = min(64, s1 - chunk);
        if (tid < cnum) { sei[tid] = ei[chunk + tid]; seb[tid] = eb[chunk + tid]; }
        __syncthreads();
        for (int j = 0; j < cnum; ++j) {
            int2 ep = sei[j];
            float4 b = seb[j];
            const unsigned short* zt = Z + (size_t)ep.x * NCOLS + d;
            int w = ep.y;
            ull q0 = *(const ull*)(zt + ((w      ) & 255) * DF);
            ull q1 = *(const ull*)(zt + ((w >> 8 ) & 255) * DF);
            ull q2 = *(const ull*)(zt + ((w >> 16) & 255) * DF);
            ull q3 = *(const ull*)(zt + ((w >> 24) & 255) * DF);
            float m0 = b.x * bf2f((unsigned short)q0) + b.y * bf2f((unsigned short)q1)
                     + b.z * bf2f((unsigned short)q2) + b.w * bf2f((unsigned short)q3);
            float m1 = b.x * bf2f((unsigned short)(q0 >> 16)) + b.y * bf2f((unsigned short)(q1 >> 16))
                     + b.z * bf2f((unsigned short)(q2 >> 16)) + b.w * bf2f((unsigned short)(q3 >> 16));
            float m2 = b.x * bf2f((unsigned short)(q0 >> 32)) + b.y * bf2f((unsigned short)(q1 >> 32))
                     + b.z * bf2f((unsigned short)(q2 >> 32)) + b.w * bf2f((unsigned short)(q3 >> 32));
            float m3 = b.x * bf2f((unsigned short)(q0 >> 48)) + b.y * bf2f((unsigned short)(q1 >> 48))
                     + b.z * bf2f((unsigned short)(q2 >> 48)) + b.w * bf2f((unsigned short)(q3 >> 48));
            vm0 = fmaxf(vm0, m0); vm1 = fmaxf(vm1, m1);
            vm2 = fmaxf(vm2, m2); vm3 = fmaxf(vm3, m3);
        }
        __syncthreads();
    }
    if (s1 == s0) { vm0 = vm1 = vm2 = vm3 = 0.f; }   // empty segment -> 0

    const unsigned short* zr = Z + (size_t)n * NCOLS + 25 * DF + d;
    ull qr = *(const ull*)zr;
    float z0 = bf2f((unsigned short)qr),         z1 = bf2f((unsigned short)(qr >> 16));
    float z2 = bf2f((unsigned short)(qr >> 32)), z3 = bf2f((unsigned short)(qr >> 48));
    float b0 = bias[d], b1 = bias[d + 1], b2 = bias[d + 2], b3 = bias[d + 3];
    size_t o = (size_t)n * DF + d;
    if (LAYER == 1) {
        union { unsigned short u[4]; ull ll; } ov;
        ov.u[0] = f2bf(fmaxf(vm0 + z0 + b0, 0.f));
        ov.u[1] = f2bf(fmaxf(vm1 + z1 + b1, 0.f));
        ov.u[2] = f2bf(fmaxf(vm2 + z2 + b2, 0.f));
        ov.u[3] = f2bf(fmaxf(vm3 + z3 + b3, 0.f));
        *(ull*)(h1b + o) = ov.ll;
    } else {
        float4 dv = *(const float4*)(descs + o);
        float4 r;
        r.x = dv.x + 0.1f * (vm0 + z0 + b0);
        r.y = dv.y + 0.1f * (vm1 + z1 + b1);
        r.z = dv.z + 0.1f * (vm2 + z2 + b2);
        r.w = dv.w + 0.1f * (vm3 + z3 + b3);
        *(float4*)(out + o) = r;
    }
}

extern "C" void kernel_launch(void* const* d_in, const int* in_sizes, int n_in,
                              void* d_out, int out_size, void* d_ws, size_t ws_size,
                              hipStream_t stream) {
    const float* descs = (const float*)d_in[0];
    const float* pts   = (const float*)d_in[1];
    const float* W1    = (const float*)d_in[2];
    const float* root1 = (const float*)d_in[3];
    const float* bias1 = (const float*)d_in[4];
    const float* W2    = (const float*)d_in[5];
    const float* root2 = (const float*)d_in[6];
    const float* bias2 = (const float*)d_in[7];
    const int* tails   = (const int*)d_in[8];
    const int* heads   = (const int*)d_in[9];
    float* out = (float*)d_out;

    char* ws = (char*)d_ws;
    unsigned short* Wbt = (unsigned short*)ws;  ws += (size_t)NMAT * DF * DF * 2;   // 54.5 MB
    unsigned short* xb  = (unsigned short*)ws;  ws += (size_t)DN * DF * 2;          //  8.4 MB
    unsigned short* h1b = (unsigned short*)ws;  ws += (size_t)DN * DF * 2;          //  8.4 MB
    unsigned short* Z   = (unsigned short*)ws;  ws += (size_t)DN * NCOLS * 2;       // 218 MB
    int*  cnt     = (int*)ws;   ws += DN * 4;
    int*  row_off = (int*)ws;   ws += (DN + 1) * 4 + 4;   // keep alignment
    int*  cursor  = (int*)ws;   ws += DN * 4;
    int2* ei      = (int2*)ws;  ws += (size_t)DE * 8;
    float4* eb    = (float4*)ws; ws += (size_t)DE * 16;

    // ---- graph structure (shared by both layers) ----
    hipMemsetAsync(cnt, 0, DN * 4, stream);
    k_convert_x<<<DN * DF / 4 / 256, 256, 0, stream>>>(descs, xb);
    k_hist<<<DE / 256, 256, 0, stream>>>(heads, cnt);
    k_scan<<<1, 1024, 0, stream>>>(cnt, row_off, cursor);
    k_scatter<<<DE / 256, 256, 0, stream>>>(pts, tails, heads, cursor, ei, eb);

    // ---- layer 1 ----
    k_transpose_w<<<dim3(16, 16, NMAT), 256, 0, stream>>>(W1, root1, Wbt);
    k_gemm<<<dim3(DN / 128, NCOLS / 128), 256, 0, stream>>>(xb, Wbt, Z);
    k_agg<1><<<DN, 256, 0, stream>>>(row_off, ei, eb, Z, bias1, nullptr, h1b, nullptr);

    // ---- layer 2 ----
    k_transpose_w<<<dim3(16, 16, NMAT), 256, 0, stream>>>(W2, root2, Wbt);
    k_gemm<<<dim3(DN / 128, NCOLS / 128), 256, 0, stream>>>(h1b, Wbt, Z);
    k_agg<2><<<DN, 256, 0, stream>>>(row_off, ei, eb, Z, bias2, descs, nullptr, out);
}